// Round 5
// baseline (1109.094 us; speedup 1.0000x reference)
//
#include <hip/hip_runtime.h>

#define N_NODES 50000
#define N_EDGES 600000
#define H 128

typedef __bf16 bf16x8 __attribute__((ext_vector_type(8)));
typedef float f32x4 __attribute__((ext_vector_type(4)));
typedef unsigned short u16;
typedef u16 u16x8 __attribute__((ext_vector_type(8)));

// d_ws layout (bytes):
//   wt: 11 matrices [128][128] bf16 transposed ([n][k])
//     0:E_W1a 1:E_W1b 2:E_W1c 3:E_W2 4:E_W3 5:E_W4 6:N_W1a 7:N_W1b 8:N_W2 9:N_W3 10:N_W4
#define MW 16384
#define WT_BYTES (11 * MW * 2)                     // 360448
#define XA_OFF WT_BYTES
#define NODE_B (N_NODES * H * 2)                   // 12800000
#define XB_OFF (XA_OFF + NODE_B)
#define XN_OFF (XB_OFF + NODE_B)
#define AUX_OFF (XN_OFF + NODE_B)                  // 38760448
// CSR area (gather path) or agg (fallback path)
#define CNT_OFF  AUX_OFF
#define BASE_OFF (CNT_OFF + 200064)
#define CUR_OFF  (BASE_OFF + 200064)
#define LIST_OFF (CUR_OFF + 200064)
#define NEB_OFF  (LIST_OFF + 2400000)              // 41961088-ish, 64B aligned
#define WS_NEED  (NEB_OFF + (size_t)N_EDGES * H * 2)
#define AGG_OFF  AUX_OFF                           // fallback f32 agg

__device__ inline u16 f2bf(float f) { return __builtin_bit_cast(u16, (__bf16)f); }
__device__ inline float bf2f(u16 u) {
  unsigned v = (unsigned)u << 16;
  return __builtin_bit_cast(float, v);
}

__device__ inline u16x8 cvt8(const float* __restrict__ p) {
  const float4 f0 = ((const float4*)p)[0];
  const float4 f1 = ((const float4*)p)[1];
  u16x8 o;
  o[0] = f2bf(f0.x); o[1] = f2bf(f0.y); o[2] = f2bf(f0.z); o[3] = f2bf(f0.w);
  o[4] = f2bf(f1.x); o[5] = f2bf(f1.y); o[6] = f2bf(f1.z); o[7] = f2bf(f1.w);
  return o;
}

__global__ __launch_bounds__(256) void prep_weights(
    const float* __restrict__ ew1, const float* __restrict__ ew2,
    const float* __restrict__ ew3, const float* __restrict__ ew4,
    const float* __restrict__ nw1, const float* __restrict__ nw2,
    const float* __restrict__ nw3, const float* __restrict__ nw4,
    u16* __restrict__ wt)
{
  const int gid = blockIdx.x * 256 + threadIdx.x;
  if (gid >= 11 * MW) return;
  const int mat = gid >> 14, idx = gid & (MW - 1);
  const int n = idx >> 7, k = idx & 127;
  const float* src; int ro = 0;
  switch (mat) {
    case 0: src = ew1; ro = 0;   break;
    case 1: src = ew1; ro = 128; break;
    case 2: src = ew1; ro = 256; break;
    case 3: src = ew2; break;
    case 4: src = ew3; break;
    case 5: src = ew4; break;
    case 6: src = nw1; ro = 0;   break;
    case 7: src = nw1; ro = 128; break;
    case 8: src = nw2; break;
    case 9: src = nw3; break;
    default: src = nw4; break;
  }
  wt[gid] = f2bf(src[(ro + k) * H + n]);
}

// ---- CSR build ----
__global__ __launch_bounds__(256) void hist_kernel(
    const int* __restrict__ eidx, int* __restrict__ cnt)
{
  const int e = blockIdx.x * 256 + threadIdx.x;
  if (e < N_EDGES) atomicAdd(&cnt[eidx[N_EDGES + e]], 1);
}

__global__ __launch_bounds__(1024) void scan_kernel(
    const int* __restrict__ cnt, int* __restrict__ base, int* __restrict__ cur)
{
  __shared__ int part[1024];
  const int t = threadIdx.x;
  const int CH = 49;   // 1024*49 = 50176 >= 50001
  const int s0 = t * CH;
  int sum = 0;
  for (int i = 0; i < CH; ++i) {
    const int idx = s0 + i;
    if (idx < N_NODES) sum += cnt[idx];
  }
  part[t] = sum;
  __syncthreads();
  for (int d = 1; d < 1024; d <<= 1) {
    const int v = t >= d ? part[t - d] : 0;
    __syncthreads();
    part[t] += v;
    __syncthreads();
  }
  int run = t > 0 ? part[t - 1] : 0;
  for (int i = 0; i < CH; ++i) {
    const int idx = s0 + i;
    if (idx <= N_NODES) {
      base[idx] = run;
      if (idx < N_NODES) { cur[idx] = run; run += cnt[idx]; }
    }
  }
}

__global__ __launch_bounds__(256) void scatter_kernel(
    const int* __restrict__ eidx, int* __restrict__ cur, int* __restrict__ list)
{
  const int e = blockIdx.x * 256 + threadIdx.x;
  if (e < N_EDGES) {
    const int p = atomicAdd(&cur[eidx[N_EDGES + e]], 1);
    list[p] = e;
  }
}

// mfma_f32_16x16x32_bf16 layouts (HW-verified R1, absmax 0.031):
//   A: row = lane&15, k = (lane>>4)*8 + j
//   B: col = lane&15, k = (lane>>4)*8 + j
//   D: col = lane&15, row = (lane>>4)*4 + reg

__global__ __launch_bounds__(256) void precompute(
    const float* __restrict__ x, const u16* __restrict__ wt,
    u16* __restrict__ xa, u16* __restrict__ xb, u16* __restrict__ xn)
{
  const int tid = threadIdx.x;
  const int lane = tid & 63, w = tid >> 6;
  const int n0 = blockIdx.x * 64 + w * 16;
  const int la = lane & 15, kg = lane >> 4;
  const int row = n0 + la < N_NODES ? n0 + la : N_NODES - 1;

  u16x8 af[4];
#pragma unroll
  for (int k0 = 0; k0 < 4; ++k0)
    af[k0] = cvt8(x + (size_t)row * H + k0 * 32 + kg * 8);

  const int mats[3] = {0, 1, 6};
  u16* outs[3] = {xa, xb, xn};
#pragma unroll
  for (int m = 0; m < 3; ++m) {
    const u16* wm = wt + mats[m] * MW;
    f32x4 acc[8];
#pragma unroll
    for (int n = 0; n < 8; ++n) acc[n] = {0.f, 0.f, 0.f, 0.f};
#pragma unroll
    for (int k0 = 0; k0 < 4; ++k0) {
      const bf16x8 a = __builtin_bit_cast(bf16x8, af[k0]);
#pragma unroll
      for (int n = 0; n < 8; ++n) {
        const u16x8 bv = *(const u16x8*)(wm + (n * 16 + la) * 128 + k0 * 32 + kg * 8);
        acc[n] = __builtin_amdgcn_mfma_f32_16x16x32_bf16(
            a, __builtin_bit_cast(bf16x8, bv), acc[n], 0, 0, 0);
      }
    }
    u16* out = outs[m];
#pragma unroll
    for (int r = 0; r < 4; ++r) {
      const int rg = n0 + kg * 4 + r;
      if (rg < N_NODES) {
#pragma unroll
        for (int n = 0; n < 8; ++n)
          out[(size_t)rg * H + n * 16 + la] = f2bf(acc[n][r]);
      }
    }
  }
}

template<int USE_NEB>
__global__ __launch_bounds__(256, 4) void edge_kernel(
    const float* __restrict__ ea, const int* __restrict__ eidx,
    const u16* __restrict__ wt,
    const u16* __restrict__ xag, const u16* __restrict__ xbg,
    const float* __restrict__ b1, const float* __restrict__ b2,
    const float* __restrict__ b3, const float* __restrict__ b4,
    const float* __restrict__ g, const float* __restrict__ be,
    float* __restrict__ out2, float* __restrict__ agg, u16* __restrict__ neb)
{
  __shared__ u16 sH[4][4096];   // per-wave [32][128] bf16 tile (8 KiB)
  const int tid = threadIdx.x;
  const int lane = tid & 63, w = tid >> 6;
  const int e0 = blockIdx.x * 128 + w * 32;
  const int la = lane & 15, kg = lane >> 4;
  const int* __restrict__ snd = eidx;
  const int* __restrict__ rcv = eidx + N_EDGES;
  u16* tile = sH[w];
  char* tileB = (char*)tile;
  const int swzA = (la & 7) << 4;

  int rA[2];
  rA[0] = e0 + la;      if (rA[0] >= N_EDGES) rA[0] = N_EDGES - 1;
  rA[1] = e0 + 16 + la; if (rA[1] >= N_EDGES) rA[1] = N_EDGES - 1;

  u16x8 af[2][4];
#pragma unroll
  for (int t = 0; t < 2; ++t)
#pragma unroll
    for (int k0 = 0; k0 < 4; ++k0)
      af[t][k0] = cvt8(ea + (size_t)rA[t] * H + k0 * 32 + kg * 8);

  // ---- L1c: S = ea @ W1c ----
  f32x4 acc[2][8];
#pragma unroll
  for (int t = 0; t < 2; ++t)
#pragma unroll
    for (int n = 0; n < 8; ++n) acc[t][n] = {0.f, 0.f, 0.f, 0.f};
  {
    const u16* wm = wt + 2 * MW;
#pragma unroll
    for (int k0 = 0; k0 < 4; ++k0) {
#pragma unroll
      for (int n = 0; n < 8; ++n) {
        const u16x8 bv = *(const u16x8*)(wm + (n * 16 + la) * 128 + k0 * 32 + kg * 8);
        acc[0][n] = __builtin_amdgcn_mfma_f32_16x16x32_bf16(
            __builtin_bit_cast(bf16x8, af[0][k0]), __builtin_bit_cast(bf16x8, bv),
            acc[0][n], 0, 0, 0);
        acc[1][n] = __builtin_amdgcn_mfma_f32_16x16x32_bf16(
            __builtin_bit_cast(bf16x8, af[1][k0]), __builtin_bit_cast(bf16x8, bv),
            acc[1][n], 0, 0, 0);
      }
    }
  }

  // store S + b1 to LDS; acc/af die -> register headroom
#pragma unroll
  for (int t = 0; t < 2; ++t)
#pragma unroll
    for (int n = 0; n < 8; ++n) {
      const float bb = b1[n * 16 + la];
#pragma unroll
      for (int r = 0; r < 4; ++r) {
        const int lr = t * 16 + kg * 4 + r;
        *(u16*)(tileB + lr * 256 + (((n * 16 + la) * 2) ^ ((lr & 7) << 4))) =
            f2bf(acc[t][n][r] + bb);
      }
    }

  // gather XA[snd], XB[rcv] after acc's live range
  u16x8 xa[2][4], xb[2][4];
#pragma unroll
  for (int t = 0; t < 2; ++t) {
    const size_t sb = (size_t)snd[rA[t]] * H;
    const size_t rb = (size_t)rcv[rA[t]] * H;
#pragma unroll
    for (int k0 = 0; k0 < 4; ++k0) {
      xa[t][k0] = *(const u16x8*)(xag + sb + k0 * 32 + kg * 8);
      xb[t][k0] = *(const u16x8*)(xbg + rb + k0 * 32 + kg * 8);
    }
  }

  // h1 = relu(S + b1 + XA + XB)
  u16x8 hf[2][4];
#pragma unroll
  for (int t = 0; t < 2; ++t)
#pragma unroll
    for (int k0 = 0; k0 < 4; ++k0) {
      const u16x8 sv = *(const u16x8*)(tileB + (t * 16 + la) * 256 +
                                       ((k0 * 64 + kg * 16) ^ swzA));
      u16x8 o;
#pragma unroll
      for (int j = 0; j < 8; ++j) {
        float v = bf2f(sv[j]) + bf2f(xa[t][k0][j]) + bf2f(xb[t][k0][j]);
        o[j] = f2bf(v > 0.f ? v : 0.f);
      }
      hf[t][k0] = o;
    }

  // ---- layers 2..4 ----
#pragma unroll
  for (int L = 0; L < 3; ++L) {
    const u16* wm = wt + (3 + L) * MW;
    const float* bias = L == 0 ? b2 : (L == 1 ? b3 : b4);
#pragma unroll
    for (int t = 0; t < 2; ++t)
#pragma unroll
      for (int n = 0; n < 8; ++n) acc[t][n] = {0.f, 0.f, 0.f, 0.f};
#pragma unroll
    for (int k0 = 0; k0 < 4; ++k0) {
#pragma unroll
      for (int n = 0; n < 8; ++n) {
        const u16x8 bv = *(const u16x8*)(wm + (n * 16 + la) * 128 + k0 * 32 + kg * 8);
        acc[0][n] = __builtin_amdgcn_mfma_f32_16x16x32_bf16(
            __builtin_bit_cast(bf16x8, hf[0][k0]), __builtin_bit_cast(bf16x8, bv),
            acc[0][n], 0, 0, 0);
        acc[1][n] = __builtin_amdgcn_mfma_f32_16x16x32_bf16(
            __builtin_bit_cast(bf16x8, hf[1][k0]), __builtin_bit_cast(bf16x8, bv),
            acc[1][n], 0, 0, 0);
      }
    }
    if (L == 2) break;
#pragma unroll
    for (int t = 0; t < 2; ++t)
#pragma unroll
      for (int n = 0; n < 8; ++n) {
        const float bb = bias[n * 16 + la];
#pragma unroll
        for (int r = 0; r < 4; ++r) {
          const int lr = t * 16 + kg * 4 + r;
          float v = acc[t][n][r] + bb;
          v = v > 0.f ? v : 0.f;
          *(u16*)(tileB + lr * 256 + (((n * 16 + la) * 2) ^ ((lr & 7) << 4))) = f2bf(v);
        }
      }
#pragma unroll
    for (int t = 0; t < 2; ++t)
#pragma unroll
      for (int k0 = 0; k0 < 4; ++k0)
        hf[t][k0] = *(const u16x8*)(tileB + (t * 16 + la) * 256 +
                                    ((k0 * 64 + kg * 16) ^ swzA));
  }

  // ---- bias4 + LayerNorm ----
  float vs[2][4], vq[2][4];
#pragma unroll
  for (int t = 0; t < 2; ++t)
#pragma unroll
    for (int r = 0; r < 4; ++r) { vs[t][r] = 0.f; vq[t][r] = 0.f; }
#pragma unroll
  for (int t = 0; t < 2; ++t)
#pragma unroll
    for (int n = 0; n < 8; ++n) {
      const float bb = b4[n * 16 + la];
#pragma unroll
      for (int r = 0; r < 4; ++r) {
        const float v = acc[t][n][r] + bb;
        acc[t][n][r] = v;
        vs[t][r] += v; vq[t][r] += v * v;
      }
    }
#pragma unroll
  for (int d = 1; d < 16; d <<= 1)
#pragma unroll
    for (int t = 0; t < 2; ++t)
#pragma unroll
      for (int r = 0; r < 4; ++r) {
        vs[t][r] += __shfl_xor(vs[t][r], d, 64);
        vq[t][r] += __shfl_xor(vq[t][r], d, 64);
      }

  if (USE_NEB) {
    // write normalized ne (bf16) into the (free) LDS tile in D-layout
#pragma unroll
    for (int t = 0; t < 2; ++t)
#pragma unroll
      for (int r = 0; r < 4; ++r) {
        const float mean = vs[t][r] * (1.0f / 128.0f);
        const float var = vq[t][r] * (1.0f / 128.0f) - mean * mean;
        const float rstd = rsqrtf(var + 1e-5f);
        const int lr = t * 16 + kg * 4 + r;
#pragma unroll
        for (int n = 0; n < 8; ++n) {
          const int col = n * 16 + la;
          const float ne = (acc[t][n][r] - mean) * rstd * g[col] + be[col];
          *(u16*)(tileB + lr * 256 + ((col * 2) ^ ((lr & 7) << 4))) = f2bf(ne);
        }
      }
    // read back in A-layout: coalesced 16B stores to neb, 16B ea loads + out2 stores
#pragma unroll
    for (int t = 0; t < 2; ++t) {
      const int rowg = e0 + t * 16 + la;
      if (rowg < N_EDGES) {
        const int lr = t * 16 + la;
        const int sw = (lr & 7) << 4;
#pragma unroll
        for (int k0 = 0; k0 < 4; ++k0) {
          const u16x8 nv = *(const u16x8*)(tileB + lr * 256 + ((k0 * 64 + kg * 16) ^ sw));
          *(u16x8*)(neb + (size_t)rowg * H + k0 * 32 + kg * 8) = nv;
          const float* ep = ea + (size_t)rowg * H + k0 * 32 + kg * 8;
          const float4 e0v = ((const float4*)ep)[0];
          const float4 e1v = ((const float4*)ep)[1];
          float4 o0, o1;
          o0.x = e0v.x + bf2f(nv[0]); o0.y = e0v.y + bf2f(nv[1]);
          o0.z = e0v.z + bf2f(nv[2]); o0.w = e0v.w + bf2f(nv[3]);
          o1.x = e1v.x + bf2f(nv[4]); o1.y = e1v.y + bf2f(nv[5]);
          o1.z = e1v.z + bf2f(nv[6]); o1.w = e1v.w + bf2f(nv[7]);
          float* op = out2 + (size_t)rowg * H + k0 * 32 + kg * 8;
          ((float4*)op)[0] = o0;
          ((float4*)op)[1] = o1;
        }
      }
    }
  } else {
    // fallback: f32 atomics into agg
#pragma unroll
    for (int t = 0; t < 2; ++t)
#pragma unroll
      for (int r = 0; r < 4; ++r) {
        const int rowg = e0 + t * 16 + kg * 4 + r;
        if (rowg < N_EDGES) {
          const float mean = vs[t][r] * (1.0f / 128.0f);
          const float var = vq[t][r] * (1.0f / 128.0f) - mean * mean;
          const float rstd = rsqrtf(var + 1e-5f);
          const int rv = rcv[rowg];
          const size_t rbase = (size_t)rowg * H;
          const size_t abase = (size_t)rv * H;
#pragma unroll
          for (int n = 0; n < 8; ++n) {
            const int col = n * 16 + la;
            const float ne = (acc[t][n][r] - mean) * rstd * g[col] + be[col];
            out2[rbase + col] = ea[rbase + col] + ne;
            atomicAdd(agg + abase + col, ne);
          }
        }
      }
  }
}

template<int USE_NEB>
__global__ __launch_bounds__(256, 4) void node_kernel(
    const float* __restrict__ x, const float* __restrict__ agg,
    const u16* __restrict__ wt, const u16* __restrict__ xng,
    const u16* __restrict__ neb, const int* __restrict__ base,
    const int* __restrict__ list,
    const float* __restrict__ b1, const float* __restrict__ b2,
    const float* __restrict__ b3, const float* __restrict__ b4,
    const float* __restrict__ g, const float* __restrict__ be,
    float* __restrict__ out1)
{
  __shared__ u16 sH[4][2048];
  const int tid = threadIdx.x;
  const int lane = tid & 63, w = tid >> 6;
  const int n0 = blockIdx.x * 64 + w * 16;
  const int la = lane & 15, kg = lane >> 4;
  u16* tile = sH[w];
  char* tileB = (char*)tile;
  const int swzA = (la & 7) << 4;

  const int row = n0 + la < N_NODES ? n0 + la : N_NODES - 1;

  u16x8 af[4];
  if (USE_NEB) {
    float facc[4][8];
#pragma unroll
    for (int k0 = 0; k0 < 4; ++k0)
#pragma unroll
      for (int j = 0; j < 8; ++j) facc[k0][j] = 0.f;
    const int pend = base[row + 1];
    for (int p = base[row]; p < pend; ++p) {
      const int e = list[p];
      const u16* nb = neb + (size_t)e * H + kg * 8;
#pragma unroll
      for (int k0 = 0; k0 < 4; ++k0) {
        const u16x8 v = *(const u16x8*)(nb + k0 * 32);
#pragma unroll
        for (int j = 0; j < 8; ++j) facc[k0][j] += bf2f(v[j]);
      }
    }
#pragma unroll
    for (int k0 = 0; k0 < 4; ++k0) {
      u16x8 o;
#pragma unroll
      for (int j = 0; j < 8; ++j) o[j] = f2bf(facc[k0][j]);
      af[k0] = o;
    }
  } else {
#pragma unroll
    for (int k0 = 0; k0 < 4; ++k0)
      af[k0] = cvt8(agg + (size_t)row * H + k0 * 32 + kg * 8);
  }

  // L1b: S = agg @ N_W1b
  f32x4 acc[8];
#pragma unroll
  for (int n = 0; n < 8; ++n) acc[n] = {0.f, 0.f, 0.f, 0.f};
  {
    const u16* wm = wt + 7 * MW;
#pragma unroll
    for (int k0 = 0; k0 < 4; ++k0)
#pragma unroll
      for (int n = 0; n < 8; ++n) {
        const u16x8 bv = *(const u16x8*)(wm + (n * 16 + la) * 128 + k0 * 32 + kg * 8);
        acc[n] = __builtin_amdgcn_mfma_f32_16x16x32_bf16(
            __builtin_bit_cast(bf16x8, af[k0]), __builtin_bit_cast(bf16x8, bv),
            acc[n], 0, 0, 0);
      }
  }
#pragma unroll
  for (int n = 0; n < 8; ++n) {
    const float bb = b1[n * 16 + la];
#pragma unroll
    for (int r = 0; r < 4; ++r) {
      const int lr = kg * 4 + r;
      *(u16*)(tileB + lr * 256 + (((n * 16 + la) * 2) ^ ((lr & 7) << 4))) =
          f2bf(acc[n][r] + bb);
    }
  }
  u16x8 xn[4];
#pragma unroll
  for (int k0 = 0; k0 < 4; ++k0)
    xn[k0] = *(const u16x8*)(xng + (size_t)row * H + k0 * 32 + kg * 8);
  u16x8 hf[4];
#pragma unroll
  for (int k0 = 0; k0 < 4; ++k0) {
    const u16x8 sv = *(const u16x8*)(tileB + la * 256 + ((k0 * 64 + kg * 16) ^ swzA));
    u16x8 o;
#pragma unroll
    for (int j = 0; j < 8; ++j) {
      float v = bf2f(sv[j]) + bf2f(xn[k0][j]);
      o[j] = f2bf(v > 0.f ? v : 0.f);
    }
    hf[k0] = o;
  }

#pragma unroll
  for (int L = 0; L < 3; ++L) {
    const u16* wm = wt + (8 + L) * MW;
    const float* bias = L == 0 ? b2 : (L == 1 ? b3 : b4);
#pragma unroll
    for (int n = 0; n < 8; ++n) acc[n] = {0.f, 0.f, 0.f, 0.f};
#pragma unroll
    for (int k0 = 0; k0 < 4; ++k0)
#pragma unroll
      for (int n = 0; n < 8; ++n) {
        const u16x8 bv = *(const u16x8*)(wm + (n * 16 + la) * 128 + k0 * 32 + kg * 8);
        acc[n] = __builtin_amdgcn_mfma_f32_16x16x32_bf16(
            __builtin_bit_cast(bf16x8, hf[k0]), __builtin_bit_cast(bf16x8, bv),
            acc[n], 0, 0, 0);
      }
    if (L == 2) break;
#pragma unroll
    for (int n = 0; n < 8; ++n) {
      const float bb = bias[n * 16 + la];
#pragma unroll
      for (int r = 0; r < 4; ++r) {
        const int lr = kg * 4 + r;
        float v = acc[n][r] + bb;
        v = v > 0.f ? v : 0.f;
        *(u16*)(tileB + lr * 256 + (((n * 16 + la) * 2) ^ ((lr & 7) << 4))) = f2bf(v);
      }
    }
#pragma unroll
    for (int k0 = 0; k0 < 4; ++k0)
      hf[k0] = *(const u16x8*)(tileB + la * 256 + ((k0 * 64 + kg * 16) ^ swzA));
  }

  float vs[4] = {0, 0, 0, 0}, vq[4] = {0, 0, 0, 0};
#pragma unroll
  for (int n = 0; n < 8; ++n) {
    const float bb = b4[n * 16 + la];
#pragma unroll
    for (int r = 0; r < 4; ++r) {
      const float v = acc[n][r] + bb;
      acc[n][r] = v; vs[r] += v; vq[r] += v * v;
    }
  }
#pragma unroll
  for (int d = 1; d < 16; d <<= 1)
#pragma unroll
    for (int r = 0; r < 4; ++r) {
      vs[r] += __shfl_xor(vs[r], d, 64);
      vq[r] += __shfl_xor(vq[r], d, 64);
    }
#pragma unroll
  for (int r = 0; r < 4; ++r) {
    const int rowg = n0 + kg * 4 + r;
    if (rowg < N_NODES) {
      const float mean = vs[r] * (1.0f / 128.0f);
      const float var = vq[r] * (1.0f / 128.0f) - mean * mean;
      const float rstd = rsqrtf(var + 1e-5f);
      const size_t rbase = (size_t)rowg * H;
#pragma unroll
      for (int n = 0; n < 8; ++n) {
        const int col = n * 16 + la;
        const float ne = (acc[n][r] - mean) * rstd * g[col] + be[col];
        out1[rbase + col] = x[rbase + col] + ne;
      }
    }
  }
}

extern "C" void kernel_launch(void* const* d_in, const int* in_sizes, int n_in,
                              void* d_out, int out_size, void* d_ws, size_t ws_size,
                              hipStream_t stream) {
  const float* x   = (const float*)d_in[0];
  const float* ea  = (const float*)d_in[1];
  const int*   ei  = (const int*)d_in[2];
  const float* ew1 = (const float*)d_in[3];
  const float* eb1 = (const float*)d_in[4];
  const float* ew2 = (const float*)d_in[5];
  const float* eb2 = (const float*)d_in[6];
  const float* ew3 = (const float*)d_in[7];
  const float* eb3 = (const float*)d_in[8];
  const float* ew4 = (const float*)d_in[9];
  const float* eb4 = (const float*)d_in[10];
  const float* eg  = (const float*)d_in[11];
  const float* ebe = (const float*)d_in[12];
  const float* nw1 = (const float*)d_in[13];
  const float* nb1 = (const float*)d_in[14];
  const float* nw2 = (const float*)d_in[15];
  const float* nb2 = (const float*)d_in[16];
  const float* nw3 = (const float*)d_in[17];
  const float* nb3 = (const float*)d_in[18];
  const float* nw4 = (const float*)d_in[19];
  const float* nb4 = (const float*)d_in[20];
  const float* ng  = (const float*)d_in[21];
  const float* nbe = (const float*)d_in[22];

  char* ws = (char*)d_ws;
  u16* wt = (u16*)ws;
  u16* xa = (u16*)(ws + XA_OFF);
  u16* xb = (u16*)(ws + XB_OFF);
  u16* xn = (u16*)(ws + XN_OFF);
  float* out1 = (float*)d_out;
  float* out2 = out1 + (size_t)N_NODES * H;

  prep_weights<<<(11 * MW + 255) / 256, 256, 0, stream>>>(
      ew1, ew2, ew3, ew4, nw1, nw2, nw3, nw4, wt);
  precompute<<<(N_NODES + 63) / 64, 256, 0, stream>>>(x, wt, xa, xb, xn);

  if (ws_size >= WS_NEED) {
    int* cnt  = (int*)(ws + CNT_OFF);
    int* base = (int*)(ws + BASE_OFF);
    int* cur  = (int*)(ws + CUR_OFF);
    int* list = (int*)(ws + LIST_OFF);
    u16* neb  = (u16*)(ws + NEB_OFF);
    hipMemsetAsync(cnt, 0, N_NODES * sizeof(int), stream);
    hist_kernel<<<(N_EDGES + 255) / 256, 256, 0, stream>>>(ei, cnt);
    scan_kernel<<<1, 1024, 0, stream>>>(cnt, base, cur);
    scatter_kernel<<<(N_EDGES + 255) / 256, 256, 0, stream>>>(ei, cur, list);
    edge_kernel<1><<<(N_EDGES + 127) / 128, 256, 0, stream>>>(
        ea, ei, wt, xa, xb, eb1, eb2, eb3, eb4, eg, ebe, out2, nullptr, neb);
    node_kernel<1><<<(N_NODES + 63) / 64, 256, 0, stream>>>(
        x, nullptr, wt, xn, neb, base, list, nb1, nb2, nb3, nb4, ng, nbe, out1);
  } else {
    float* agg = (float*)(ws + AGG_OFF);
    hipMemsetAsync(agg, 0, (size_t)N_NODES * H * sizeof(float), stream);
    edge_kernel<0><<<(N_EDGES + 127) / 128, 256, 0, stream>>>(
        ea, ei, wt, xa, xb, eb1, eb2, eb3, eb4, eg, ebe, out2, agg, nullptr);
    node_kernel<0><<<(N_NODES + 63) / 64, 256, 0, stream>>>(
        x, agg, wt, xn, nullptr, nullptr, nullptr,
        nb1, nb2, nb3, nb4, ng, nbe, out1);
  }
}